// Round 8
// baseline (2146.731 us; speedup 1.0000x reference)
//
#include <hip/hip_runtime.h>
#include <cmath>

namespace {

constexpr int kWin = 100;
constexpr int kNin = 700;

// f32 transposed-weight offsets (floats) inside d_ws.
constexpr size_t OFF1 = 0;        // WT1 [700][512]
constexpr size_t OFF2 = 358400;   // WT2 [512][256]
constexpr size_t OFF3 = 489472;   // WT3 [256][128]
constexpr size_t OFF4 = 522240;   // WT4 [128][256]
constexpr size_t OFF5 = 555008;   // WT5 [256][512]
constexpr size_t OFF6 = 686080;   // WT6 [512][700]
constexpr size_t OFF_END = 1044480;          // floats used by weights (4.18 MB, L2-resident)
constexpr size_t XM_OFF_U64 = OFF_END / 2;   // u64 index into ws for xmasks
// xmask layout: [B=512][T=100][12] u64: words 0..10 = spike bits, word 11 = total popcount.

__global__ void transpose_k(const float* __restrict__ src, float* __restrict__ dst,
                            int H, int K) {
  int idx = blockIdx.x * blockDim.x + threadIdx.x;
  if (idx < H * K) {
    int h = idx / K;
    int k = idx - h * K;
    dst[(size_t)k * H + h] = src[idx];  // dst[K][H] = src[H][K]^T
  }
}

// Build input spike bitmasks + total count: one block per (row, t), 256 threads.
// Word w covers input neurons h in [w*64, w*64+64), bit = h%64. dst[11] = total.
__global__ __launch_bounds__(256) void xmask_k(const float* __restrict__ x,
                                               unsigned long long* __restrict__ xm) {
  const int bid = blockIdx.x;  // row * 100 + t
  const int tid = threadIdx.x;
  const int lane = tid & 63;
  const int wv = tid >> 6;  // 0..3
  const float* xr = x + (size_t)bid * kNin;
  unsigned long long* dst = xm + (size_t)bid * 12;
  __shared__ int sc[4];
  int tc = 0;
#pragma unroll
  for (int s = 0; s < 3; ++s) {
    const int h = s * 256 + tid;
    const bool p = (h < kNin) ? (xr[h] != 0.0f) : false;
    const unsigned long long b = __ballot(p);
    const int idx = s * 4 + wv;
    tc += (int)__popcll(b);  // idx==11 ballot covers h>=704 -> 0, contributes 0
    if (lane == 0 && idx < 11) dst[idx] = b;
  }
  if (lane == 0) sc[wv] = tc;
  __syncthreads();
  if (tid == 0)
    dst[11] = (unsigned long long)((sc[0] + sc[1]) + (sc[2] + sc[3]));
}

// One LIF layer (R2/R7 skeleton, verified passing). 1024 threads per batch row.
// R8 delta: contiguous-rank work partition. Each mask carries its total active
// count; group kp takes active-column ranks [kp*Q, min((kp+1)*Q, tot)),
// Q = ceil(tot/4) -> perfect +-1 balance across the 4 groups in every layer
// (replaces the chunk-mod-4 partition whose structural+statistical skew made
// every barrier wait on the slowest group). Walk machinery (u32 chunks,
// rolling prefetch, ctz/clear, 4/1 bodies) identical to R7; only scalar
// rank-window bookkeeping added. Summation order remains fixed/deterministic.
// mem_new = mem*alpha + sum(active WT columns); spike = mem_new > 0.3;
// mem = (mem_new < 0.3) ? mem_new : 0.  ((1-o_spike) factor is redundant:
// the hard reset already zeroed spiking neurons; VRESET = 0.)
template <int K, int H, bool BUILD, typename FCh>
__device__ __forceinline__ void lif(const float* __restrict__ WT, FCh&& chunk,
                                    int tot,
                                    double* mem, unsigned long long* mOut,
                                    int* mcOut,
                                    double (*part)[3][256],  // [kp][s][ht]
                                    float* outRow,
                                    int kp, int ht, int lane, int wv4,
                                    double alpha) {
  constexpr int NS = (H + 255) / 256;
  constexpr int NC = (K + 31) / 32;  // 32-bit mask chunks
  double acc[NS];
#pragma unroll
  for (int s = 0; s < NS; ++s) acc[s] = 0.0;

  // Rank window for this group.
  const int Q = (tot + 3) >> 2;
  const int rlo = kp * Q;
  const int rhiA = rlo + Q;
  const int rhi = (rhiA < tot) ? rhiA : tot;

  unsigned mNext = chunk(0);  // rolling prefetch (R7)
  int cum = 0;
  for (int c = 0; c < NC && cum < rhi; ++c) {
    unsigned m = __builtin_amdgcn_readfirstlane(mNext);
    if (c + 1 < NC) mNext = chunk(c + 1);
    const int pc = __builtin_popcount(m);
    const int lo = (cum > rlo) ? cum : rlo;
    const int hiA = cum + pc;
    const int hi = (hiA < rhi) ? hiA : rhi;
    cum = hiA;
    if (lo >= hi) continue;
    const int nskip = lo - (hiA - pc);
    for (int i = 0; i < nskip; ++i) m &= m - 1;  // skip pre-window bits
    const int n = hi - lo;  // bits to take from this chunk
    const float* __restrict__ cbase = WT + (size_t)c * 32 * H;
    int i = 0;
    for (; i + 4 <= n; i += 4) {
      const int b0 = __builtin_ctz(m); m &= m - 1;
      const int b1 = __builtin_ctz(m); m &= m - 1;
      const int b2 = __builtin_ctz(m); m &= m - 1;
      const int b3 = __builtin_ctz(m); m &= m - 1;
      const float* p0 = cbase + b0 * H;
      const float* p1 = cbase + b1 * H;
      const float* p2 = cbase + b2 * H;
      const float* p3 = cbase + b3 * H;
#pragma unroll
      for (int s = 0; s < NS; ++s) {
        const int h = s * 256 + ht;
        if ((s + 1) * 256 <= H || h < H) {
          const float f0 = p0[h];
          const float f1 = p1[h];
          const float f2 = p2[h];
          const float f3 = p3[h];
          const double t01 = (double)f0 + (double)f1;  // tree reassociation
          const double t23 = (double)f2 + (double)f3;
          acc[s] += t01 + t23;
        }
      }
    }
    for (; i < n; ++i) {
      const int b0 = __builtin_ctz(m); m &= m - 1;
      const float* p0 = cbase + b0 * H;
#pragma unroll
      for (int s = 0; s < NS; ++s) {
        const int h = s * 256 + ht;
        if ((s + 1) * 256 <= H || h < H) acc[s] += (double)p0[h];
      }
    }
  }

#pragma unroll
  for (int s = 0; s < NS; ++s) part[kp][s][ht] = acc[s];
  __syncthreads();  // SYNC1: partials ready

  bool pred[NS];
#pragma unroll
  for (int s = 0; s < NS; ++s) {
    const int h = s * 256 + ht;
    if ((s + 1) * 256 <= H || h < H) {
      const double p01 = part[0][s][ht] + part[1][s][ht];
      const double tot2 = (p01 + part[2][s][ht]) + part[3][s][ht];
      const double mm = mem[s] * alpha + tot2;
      pred[s] = (mm > 0.3);
      mem[s] = (mm < 0.3) ? mm : 0.0;
      if (!BUILD) {
        if (kp == s) outRow[h] = pred[s] ? 1.0f : 0.0f;  // slot s stored by kp==s
      }
    } else {
      pred[s] = false;
    }
  }
  if (BUILD) {
    int cw = 0;
#pragma unroll
    for (int s = 0; s < NS; ++s) {
      const unsigned long long b = __ballot(pred[s]);
      cw += (int)__popcll(b);
      if (kp == 0 && lane == 0) mOut[s * 4 + wv4] = b;
    }
    if (kp == 0 && lane == 0) mcOut[wv4] = cw;  // per-wave count for next tot
    __syncthreads();  // SYNC2: next layer's mask + counts ready
  }
}

// 512 blocks x 1024 threads, one batch row per block. Steps 0..4 of the
// reference (zero-padded input) provably keep all state at 0, so only the
// 100 live steps run.
__global__ __launch_bounds__(1024, 8) void snn_main(
    const float* __restrict__ wsf, const unsigned long long* __restrict__ xmask,
    float* __restrict__ out) {
  const int tid = threadIdx.x;
  const int kp = tid >> 8;         // 0..3
  const int ht = tid & 255;
  const int lane = tid & 63;
  const int wv4 = (tid >> 6) & 3;  // wave index within kp group
  const int row = blockIdx.x;

  const float* WT1 = wsf + OFF1;
  const float* WT2 = wsf + OFF2;
  const float* WT3 = wsf + OFF3;
  const float* WT4 = wsf + OFF4;
  const float* WT5 = wsf + OFF5;
  const float* WT6 = wsf + OFF6;

  __shared__ alignas(16) unsigned long long mk[2][12];
  __shared__ alignas(16) int mc[2][4];    // per-wave spike counts (for totals)
  __shared__ double parts[2][4][3][256];  // [pingpong][kp][s][ht]

  // Per-thread membrane state (f64); slot s covers neuron h = s*256 + ht.
  double m1[2] = {0.0, 0.0};
  double m2[1] = {0.0};
  double m3[1] = {0.0};
  double m4[1] = {0.0};
  double m5[2] = {0.0, 0.0};
  double m6[3] = {0.0, 0.0, 0.0};

  const double alpha = exp(-1.0 / 3.0);

  const unsigned long long* xmRow = xmask + (size_t)row * kWin * 12;
  float* outRowBase = out + (size_t)row * kWin * kNin;

  for (int t = 0; t < kWin; ++t) {
    const unsigned* xm32 = (const unsigned*)(xmRow + (size_t)t * 12);
    const unsigned* mk0 = (const unsigned*)&mk[0][0];
    const unsigned* mk1 = (const unsigned*)&mk[1][0];

    const int totX = (int)xm32[22];  // low half of u64 word 11 = total
    lif<700, 512, true>(WT1, [&](int c) { return xm32[c]; }, totX, m1, mk[0],
                        mc[0], parts[0], nullptr, kp, ht, lane, wv4, alpha);
    {
      const int4 v = *(const int4*)&mc[0][0];
      lif<512, 256, true>(WT2, [&](int c) { return mk0[c]; },
                          (v.x + v.y) + (v.z + v.w), m2, mk[1], mc[1],
                          parts[1], nullptr, kp, ht, lane, wv4, alpha);
    }
    {
      const int4 v = *(const int4*)&mc[1][0];
      lif<256, 128, true>(WT3, [&](int c) { return mk1[c]; },
                          (v.x + v.y) + (v.z + v.w), m3, mk[0], mc[0],
                          parts[0], nullptr, kp, ht, lane, wv4, alpha);
    }
    {
      const int4 v = *(const int4*)&mc[0][0];
      lif<128, 256, true>(WT4, [&](int c) { return mk0[c]; },
                          (v.x + v.y) + (v.z + v.w), m4, mk[1], mc[1],
                          parts[1], nullptr, kp, ht, lane, wv4, alpha);
    }
    {
      const int4 v = *(const int4*)&mc[1][0];
      lif<256, 512, true>(WT5, [&](int c) { return mk1[c]; },
                          (v.x + v.y) + (v.z + v.w), m5, mk[0], mc[0],
                          parts[0], nullptr, kp, ht, lane, wv4, alpha);
    }
    {
      const int4 v = *(const int4*)&mc[0][0];
      float* outRow = outRowBase + (size_t)t * kNin;
      lif<512, 700, false>(WT6, [&](int c) { return mk0[c]; },
                           (v.x + v.y) + (v.z + v.w), m6, nullptr, nullptr,
                           parts[1], outRow, kp, ht, lane, wv4, alpha);
    }
  }
}

}  // namespace

extern "C" void kernel_launch(void* const* d_in, const int* in_sizes, int n_in,
                              void* d_out, int out_size, void* d_ws, size_t ws_size,
                              hipStream_t stream) {
  const float* x = (const float*)d_in[0];
  float* ws = (float*)d_ws;
  unsigned long long* xm = (unsigned long long*)d_ws + XM_OFF_U64;
  float* out = (float*)d_out;

  // Transpose all weights into workspace (f32): dst[K][H] = W[H][K]^T.
  struct TK { int H, K; size_t off; int idx; };
  const TK tk[6] = {
      {512, 700, OFF1, 1},  // W_ih1
      {256, 512, OFF2, 2},  // W_h1h2
      {128, 256, OFF3, 3},  // W_h2h3
      {256, 128, OFF4, 4},  // W_h3h2
      {512, 256, OFF5, 5},  // W_h2h1
      {700, 512, OFF6, 6},  // W_h1o
  };
  for (int i = 0; i < 6; ++i) {
    const int n = tk[i].H * tk[i].K;
    transpose_k<<<(n + 255) / 256, 256, 0, stream>>>(
        (const float*)d_in[tk[i].idx], ws + tk[i].off, tk[i].H, tk[i].K);
  }

  // Precompute input spike bitmasks + totals for all (row, t).
  xmask_k<<<512 * kWin, 256, 0, stream>>>(x, xm);

  snn_main<<<512, 1024, 0, stream>>>(ws, xm, out);
}

// Round 9
// 1301.836 us; speedup vs baseline: 1.6490x; 1.6490x over previous
//
#include <hip/hip_runtime.h>
#include <cmath>

namespace {

constexpr int kWin = 100;
constexpr int kNin = 700;

// f32 transposed-weight offsets (floats) inside d_ws.
constexpr size_t OFF1 = 0;        // WT1 [700][512]
constexpr size_t OFF2 = 358400;   // WT2 [512][256]
constexpr size_t OFF3 = 489472;   // WT3 [256][128]
constexpr size_t OFF4 = 522240;   // WT4 [128][256]
constexpr size_t OFF5 = 555008;   // WT5 [256][512]
constexpr size_t OFF6 = 686080;   // WT6 [512][700]
constexpr size_t OFF_END = 1044480;          // floats used by weights (4.18 MB, L2-resident)
constexpr size_t XM_OFF_U64 = OFF_END / 2;   // u64 index into ws for xmasks
// xmask layout: [B=512][T=100][12] u64 words (11 used + 1 pad, always written)

__global__ void transpose_k(const float* __restrict__ src, float* __restrict__ dst,
                            int H, int K) {
  int idx = blockIdx.x * blockDim.x + threadIdx.x;
  if (idx < H * K) {
    int h = idx / K;
    int k = idx - h * K;
    dst[(size_t)k * H + h] = src[idx];  // dst[K][H] = src[H][K]^T
  }
}

// Build input spike bitmasks: one block per (row, t), 256 threads.
// Word w covers input neurons h in [w*64, w*64+64), bit = h%64.
__global__ __launch_bounds__(256) void xmask_k(const float* __restrict__ x,
                                               unsigned long long* __restrict__ xm) {
  const int bid = blockIdx.x;  // row * 100 + t
  const int tid = threadIdx.x;
  const int lane = tid & 63;
  const int wv = tid >> 6;  // 0..3
  const float* xr = x + (size_t)bid * kNin;
  unsigned long long* dst = xm + (size_t)bid * 12;
#pragma unroll
  for (int s = 0; s < 3; ++s) {
    const int h = s * 256 + tid;
    const bool p = (h < kNin) ? (xr[h] != 0.0f) : false;
    const unsigned long long b = __ballot(p);
    if (lane == 0) dst[s * 4 + wv] = b;  // s=2,wv=3 writes pad word 11 (= 0)
  }
}

// One LIF layer (R2/R7 skeleton, verified passing). 1024 threads per batch row:
// kp = tid>>8 splits the active-column sum 4 ways (32-bit mask chunks,
// c % 4 == kp); partials combined via LDS in the fixed order ((p0+p1)+p2)+p3.
// R9 delta (PAIR=true for the NS>=2 layers L1/L5/L6 = 81% of gather traffic):
// gather-side slot remap so each thread covers ADJACENT outputs h = 2*ht and
// 2*ht+1, loaded as one float2 (dwordx2) per column — halves load-instruction
// count and address VALU with no lane idling. For H=700 a third single slot
// h = 512+ht (ht<188) remains. Epilogue ownership (h = s*256+ht), mask/ballot
// layout, and per-h summation order are UNCHANGED — the epilogue just remaps
// its parts-read index ([h&1][h>>1] for h<512; slot 2 else).
// mem_new = mem*alpha + sum(active WT columns); spike = mem_new > 0.3;
// mem = (mem_new < 0.3) ? mem_new : 0.  ((1-o_spike) factor is redundant:
// the hard reset already zeroed spiking neurons; VRESET = 0.)
template <int K, int H, bool BUILD, bool PAIR, typename FCh>
__device__ __forceinline__ void lif(const float* __restrict__ WT, FCh&& chunk,
                                    double* mem, unsigned long long* mOut,
                                    double (*part)[3][256],  // [kp][s][ht]
                                    float* outRow,
                                    int kp, int ht, int lane, int wv4,
                                    double alpha) {
  constexpr int NS = (H + 255) / 256;
  constexpr int NC = (K + 31) / 32;  // 32-bit mask chunks
  static_assert(!PAIR || H == 512 || H == 700, "PAIR only for H=512/700");

  if constexpr (PAIR) {
    double ae = 0.0, ao = 0.0, a2 = 0.0;
    const bool s2on = (H == 700) ? (ht < H - 512) : false;
    const int ht2 = 2 * ht;

    unsigned mNext = chunk(kp);  // rolling prefetch (R7)
    for (int c = kp; c < NC; c += 4) {
      unsigned m = __builtin_amdgcn_readfirstlane(mNext);
      if (c + 4 < NC) mNext = chunk(c + 4);
      const float* __restrict__ cbase = WT + (size_t)c * 32 * H;
      const int cnt = __builtin_popcount(m);
      int i = 0;
      for (; i + 4 <= cnt; i += 4) {
        const int b0 = __builtin_ctz(m); m &= m - 1;
        const int b1 = __builtin_ctz(m); m &= m - 1;
        const int b2 = __builtin_ctz(m); m &= m - 1;
        const int b3 = __builtin_ctz(m); m &= m - 1;
        const float* p0 = cbase + b0 * H;
        const float* p1 = cbase + b1 * H;
        const float* p2 = cbase + b2 * H;
        const float* p3 = cbase + b3 * H;
        const float2 f0 = *(const float2*)(p0 + ht2);
        const float2 f1 = *(const float2*)(p1 + ht2);
        const float2 f2 = *(const float2*)(p2 + ht2);
        const float2 f3 = *(const float2*)(p3 + ht2);
        const double t01e = (double)f0.x + (double)f1.x;  // same per-h tree as R7
        const double t23e = (double)f2.x + (double)f3.x;
        ae += t01e + t23e;
        const double t01o = (double)f0.y + (double)f1.y;
        const double t23o = (double)f2.y + (double)f3.y;
        ao += t01o + t23o;
        if constexpr (H == 700) {
          if (s2on) {
            const float g0 = p0[512 + ht];
            const float g1 = p1[512 + ht];
            const float g2 = p2[512 + ht];
            const float g3 = p3[512 + ht];
            const double u01 = (double)g0 + (double)g1;
            const double u23 = (double)g2 + (double)g3;
            a2 += u01 + u23;
          }
        }
      }
      for (; i < cnt; ++i) {
        const int b0 = __builtin_ctz(m); m &= m - 1;
        const float* p0 = cbase + b0 * H;
        const float2 f0 = *(const float2*)(p0 + ht2);
        ae += (double)f0.x;
        ao += (double)f0.y;
        if constexpr (H == 700) {
          if (s2on) a2 += (double)p0[512 + ht];
        }
      }
    }
    part[kp][0][ht] = ae;  // partial for h = 2*ht
    part[kp][1][ht] = ao;  // partial for h = 2*ht+1
    if constexpr (H == 700) {
      if (s2on) part[kp][2][ht] = a2;  // partial for h = 512+ht
    }
  } else {
    double acc[NS];
#pragma unroll
    for (int s = 0; s < NS; ++s) acc[s] = 0.0;

    unsigned mNext = chunk(kp);  // rolling prefetch (R7)
    for (int c = kp; c < NC; c += 4) {
      unsigned m = __builtin_amdgcn_readfirstlane(mNext);
      if (c + 4 < NC) mNext = chunk(c + 4);
      const float* __restrict__ cbase = WT + (size_t)c * 32 * H;
      const int cnt = __builtin_popcount(m);
      int i = 0;
      for (; i + 4 <= cnt; i += 4) {
        const int b0 = __builtin_ctz(m); m &= m - 1;
        const int b1 = __builtin_ctz(m); m &= m - 1;
        const int b2 = __builtin_ctz(m); m &= m - 1;
        const int b3 = __builtin_ctz(m); m &= m - 1;
        const float* p0 = cbase + b0 * H;
        const float* p1 = cbase + b1 * H;
        const float* p2 = cbase + b2 * H;
        const float* p3 = cbase + b3 * H;
#pragma unroll
        for (int s = 0; s < NS; ++s) {
          const int h = s * 256 + ht;
          if ((s + 1) * 256 <= H || h < H) {
            const float f0 = p0[h];
            const float f1 = p1[h];
            const float f2 = p2[h];
            const float f3 = p3[h];
            const double t01 = (double)f0 + (double)f1;  // tree reassociation
            const double t23 = (double)f2 + (double)f3;
            acc[s] += t01 + t23;
          }
        }
      }
      for (; i < cnt; ++i) {
        const int b0 = __builtin_ctz(m); m &= m - 1;
        const float* p0 = cbase + b0 * H;
#pragma unroll
        for (int s = 0; s < NS; ++s) {
          const int h = s * 256 + ht;
          if ((s + 1) * 256 <= H || h < H) acc[s] += (double)p0[h];
        }
      }
    }
#pragma unroll
    for (int s = 0; s < NS; ++s) part[kp][s][ht] = acc[s];
  }
  __syncthreads();  // SYNC1: partials ready

  bool pred[NS];
#pragma unroll
  for (int s = 0; s < NS; ++s) {
    const int h = s * 256 + ht;
    if ((s + 1) * 256 <= H || h < H) {
      double q0, q1, q2, q3;
      if constexpr (PAIR) {
        if (s < 2) {  // h < 512: pair slots, partial at [h&1][h>>1]
          const int sl = ht & 1;
          const int ix = s * 128 + (ht >> 1);
          q0 = part[0][sl][ix];
          q1 = part[1][sl][ix];
          q2 = part[2][sl][ix];
          q3 = part[3][sl][ix];
        } else {  // h = 512+ht
          q0 = part[0][2][ht];
          q1 = part[1][2][ht];
          q2 = part[2][2][ht];
          q3 = part[3][2][ht];
        }
      } else {
        q0 = part[0][s][ht];
        q1 = part[1][s][ht];
        q2 = part[2][s][ht];
        q3 = part[3][s][ht];
      }
      const double p01 = q0 + q1;
      const double tot = (p01 + q2) + q3;
      const double mm = mem[s] * alpha + tot;
      pred[s] = (mm > 0.3);
      mem[s] = (mm < 0.3) ? mm : 0.0;
      if (!BUILD) {
        if (kp == s) outRow[h] = pred[s] ? 1.0f : 0.0f;  // slot s stored by kp==s
      }
    } else {
      pred[s] = false;
    }
  }
  if (BUILD) {
#pragma unroll
    for (int s = 0; s < NS; ++s) {
      const unsigned long long b = __ballot(pred[s]);
      if (kp == 0 && lane == 0) mOut[s * 4 + wv4] = b;
    }
    __syncthreads();  // SYNC2: next layer's mask ready
  }
}

// 512 blocks x 1024 threads, one batch row per block. Steps 0..4 of the
// reference (zero-padded input) provably keep all state at 0, so only the
// 100 live steps run.
__global__ __launch_bounds__(1024, 8) void snn_main(
    const float* __restrict__ wsf, const unsigned long long* __restrict__ xmask,
    float* __restrict__ out) {
  const int tid = threadIdx.x;
  const int kp = tid >> 8;         // 0..3
  const int ht = tid & 255;
  const int lane = tid & 63;
  const int wv4 = (tid >> 6) & 3;  // wave index within kp group
  const int row = blockIdx.x;

  const float* WT1 = wsf + OFF1;
  const float* WT2 = wsf + OFF2;
  const float* WT3 = wsf + OFF3;
  const float* WT4 = wsf + OFF4;
  const float* WT5 = wsf + OFF5;
  const float* WT6 = wsf + OFF6;

  __shared__ unsigned long long mk[2][12];
  __shared__ double parts[2][4][3][256];  // [pingpong][kp][s][ht]

  // Per-thread membrane state (f64); slot s covers neuron h = s*256 + ht.
  double m1[2] = {0.0, 0.0};
  double m2[1] = {0.0};
  double m3[1] = {0.0};
  double m4[1] = {0.0};
  double m5[2] = {0.0, 0.0};
  double m6[3] = {0.0, 0.0, 0.0};

  const double alpha = exp(-1.0 / 3.0);

  const unsigned long long* xmRow = xmask + (size_t)row * kWin * 12;
  float* outRowBase = out + (size_t)row * kWin * kNin;

  for (int t = 0; t < kWin; ++t) {
    const unsigned* xm32 = (const unsigned*)(xmRow + (size_t)t * 12);
    const unsigned* mk0 = (const unsigned*)&mk[0][0];
    const unsigned* mk1 = (const unsigned*)&mk[1][0];

    lif<700, 512, true, true>(WT1, [&](int c) { return xm32[c]; }, m1, mk[0],
                              parts[0], nullptr, kp, ht, lane, wv4, alpha);
    lif<512, 256, true, false>(WT2, [&](int c) { return mk0[c]; }, m2, mk[1],
                               parts[1], nullptr, kp, ht, lane, wv4, alpha);
    lif<256, 128, true, false>(WT3, [&](int c) { return mk1[c]; }, m3, mk[0],
                               parts[0], nullptr, kp, ht, lane, wv4, alpha);
    lif<128, 256, true, false>(WT4, [&](int c) { return mk0[c]; }, m4, mk[1],
                               parts[1], nullptr, kp, ht, lane, wv4, alpha);
    lif<256, 512, true, true>(WT5, [&](int c) { return mk1[c]; }, m5, mk[0],
                              parts[0], nullptr, kp, ht, lane, wv4, alpha);
    float* outRow = outRowBase + (size_t)t * kNin;
    lif<512, 700, false, true>(WT6, [&](int c) { return mk0[c]; }, m6, nullptr,
                               parts[1], outRow, kp, ht, lane, wv4, alpha);
  }
}

}  // namespace

extern "C" void kernel_launch(void* const* d_in, const int* in_sizes, int n_in,
                              void* d_out, int out_size, void* d_ws, size_t ws_size,
                              hipStream_t stream) {
  const float* x = (const float*)d_in[0];
  float* ws = (float*)d_ws;
  unsigned long long* xm = (unsigned long long*)d_ws + XM_OFF_U64;
  float* out = (float*)d_out;

  // Transpose all weights into workspace (f32): dst[K][H] = W[H][K]^T.
  struct TK { int H, K; size_t off; int idx; };
  const TK tk[6] = {
      {512, 700, OFF1, 1},  // W_ih1
      {256, 512, OFF2, 2},  // W_h1h2
      {128, 256, OFF3, 3},  // W_h2h3
      {256, 128, OFF4, 4},  // W_h3h2
      {512, 256, OFF5, 5},  // W_h2h1
      {700, 512, OFF6, 6},  // W_h1o
  };
  for (int i = 0; i < 6; ++i) {
    const int n = tk[i].H * tk[i].K;
    transpose_k<<<(n + 255) / 256, 256, 0, stream>>>(
        (const float*)d_in[tk[i].idx], ws + tk[i].off, tk[i].H, tk[i].K);
  }

  // Precompute input spike bitmasks for all (row, t).
  xmask_k<<<512 * kWin, 256, 0, stream>>>(x, xm);

  snn_main<<<512, 1024, 0, stream>>>(ws, xm, out);
}

// Round 10
// 1267.670 us; speedup vs baseline: 1.6934x; 1.0270x over previous
//
#include <hip/hip_runtime.h>
#include <cmath>

namespace {

constexpr int kWin = 100;
constexpr int kNin = 700;

// f32 transposed-weight offsets (floats) inside d_ws.
constexpr size_t OFF1 = 0;        // WT1 [700][512]
constexpr size_t OFF2 = 358400;   // WT2 [512][256]
constexpr size_t OFF3 = 489472;   // WT3 [256][128]
constexpr size_t OFF4 = 522240;   // WT4 [128][256]
constexpr size_t OFF5 = 555008;   // WT5 [256][512]
constexpr size_t OFF6 = 686080;   // WT6 [512][700]
constexpr size_t OFF_END = 1044480;          // floats used by weights (4.18 MB, L2-resident)
constexpr size_t XM_OFF_U64 = OFF_END / 2;   // u64 index into ws for xmasks
// xmask layout: [B=512][T=100][12] u64 words (11 used + 1 pad, always written)

__global__ void transpose_k(const float* __restrict__ src, float* __restrict__ dst,
                            int H, int K) {
  int idx = blockIdx.x * blockDim.x + threadIdx.x;
  if (idx < H * K) {
    int h = idx / K;
    int k = idx - h * K;
    dst[(size_t)k * H + h] = src[idx];  // dst[K][H] = src[H][K]^T
  }
}

// Build input spike bitmasks: one block per (row, t), 256 threads.
// Word w covers input neurons h in [w*64, w*64+64), bit = h%64.
__global__ __launch_bounds__(256) void xmask_k(const float* __restrict__ x,
                                               unsigned long long* __restrict__ xm) {
  const int bid = blockIdx.x;  // row * 100 + t
  const int tid = threadIdx.x;
  const int lane = tid & 63;
  const int wv = tid >> 6;  // 0..3
  const float* xr = x + (size_t)bid * kNin;
  unsigned long long* dst = xm + (size_t)bid * 12;
#pragma unroll
  for (int s = 0; s < 3; ++s) {
    const int h = s * 256 + tid;
    const bool p = (h < kNin) ? (xr[h] != 0.0f) : false;
    const unsigned long long b = __ballot(p);
    if (lane == 0) dst[s * 4 + wv] = b;  // s=2,wv=3 writes pad word 11 (= 0)
  }
}

// One LIF layer (R2/R7 epilogue skeleton; R10 list-based gather).
// Gather: the input is a packed LDS list of PRE-MULTIPLIED column element
// offsets (e = k * H). Group kp = tid>>8 takes contiguous rank quarter
// [kp*qlen, min((kp+1)*qlen, cnt)) (qlen mult-of-4 -> int4-aligned, near-
// perfect balance). Per 4 columns: one broadcast int4 LDS read (rolling
// prefetch), 4 readfirstlane -> scalar bases, NS loads each, fixed-order
// f64 tree adds (identical arithmetic to R7).
// Epilogue (unchanged math): partials combined ((p0+p1)+p2)+p3; membrane
// update; spike. BUILD: spiking lanes append h*HNEXT to the next packed list
// via one wave-level atomicAdd + rank write (deterministic within wave).
// XB (L5 only): same machinery builds the t+1 input list from a prefetched
// xmask word. mem_new = mem*alpha + sum(active cols); spike = mem_new > 0.3;
// mem = (mem_new < 0.3) ? mem_new : 0.  ((1-o_spike) is redundant: the hard
// reset already zeroed spiking neurons; VRESET = 0.)
template <int H, int HNEXT, bool BUILD, bool XB>
__device__ __forceinline__ void lif(const float* __restrict__ WT,
                                    const int* __restrict__ listIn,
                                    const int* __restrict__ cntIn,
                                    int* __restrict__ listOut,
                                    int* __restrict__ cntOut,
                                    double (*part)[3][256],  // [kp][s][ht]
                                    double* mem, double alpha,
                                    float* __restrict__ outRow,
                                    unsigned long long xw, bool doX,
                                    int* __restrict__ xList,
                                    int* __restrict__ xCnt,
                                    int kp, int ht, int lane, int wv4, int w) {
  constexpr int NS = (H + 255) / 256;
  double acc[NS];
#pragma unroll
  for (int s = 0; s < NS; ++s) acc[s] = 0.0;

  const int cnt = __builtin_amdgcn_readfirstlane(*cntIn);
  const int qlen = ((cnt + 15) >> 4) << 2;  // mult-of-4 quarter
  const int start = kp * qlen;
  const int endA = start + qlen;
  const int end = (endA < cnt) ? endA : cnt;
  const float* __restrict__ wbase = WT + ht;
  if (start < end) {
    const int n4 = (end - start) & ~3;
    const int e4 = start + n4;
    int j = start;
    if (n4 > 0) {
      int4 eC = *(const int4*)(listIn + j);
      for (; j < e4; j += 4) {
        const int jn = (j + 4 < e4) ? (j + 4) : j;  // branchless rolling prefetch
        int4 eN = *(const int4*)(listIn + jn);
        const int e0 = __builtin_amdgcn_readfirstlane(eC.x);
        const int e1 = __builtin_amdgcn_readfirstlane(eC.y);
        const int e2 = __builtin_amdgcn_readfirstlane(eC.z);
        const int e3 = __builtin_amdgcn_readfirstlane(eC.w);
        const float* p0 = wbase + e0;
        const float* p1 = wbase + e1;
        const float* p2 = wbase + e2;
        const float* p3 = wbase + e3;
#pragma unroll
        for (int s = 0; s < NS; ++s) {
          const int h = s * 256 + ht;
          if ((s + 1) * 256 <= H || h < H) {
            const float f0 = p0[s * 256];
            const float f1 = p1[s * 256];
            const float f2 = p2[s * 256];
            const float f3 = p3[s * 256];
            const double t01 = (double)f0 + (double)f1;  // R7 tree order
            const double t23 = (double)f2 + (double)f3;
            acc[s] += t01 + t23;
          }
        }
        eC = eN;
      }
    }
    for (; j < end; ++j) {  // <=3 singles per group
      const int e0 = __builtin_amdgcn_readfirstlane(listIn[j]);
      const float* p0 = wbase + e0;
#pragma unroll
      for (int s = 0; s < NS; ++s) {
        const int h = s * 256 + ht;
        if ((s + 1) * 256 <= H || h < H) acc[s] += (double)p0[s * 256];
      }
    }
  }

#pragma unroll
  for (int s = 0; s < NS; ++s) part[kp][s][ht] = acc[s];
  __syncthreads();  // SYNC1: partials ready

  bool pred[NS];
#pragma unroll
  for (int s = 0; s < NS; ++s) {
    const int h = s * 256 + ht;
    if ((s + 1) * 256 <= H || h < H) {
      const double p01 = part[0][s][ht] + part[1][s][ht];
      const double tot = (p01 + part[2][s][ht]) + part[3][s][ht];
      const double mm = mem[s] * alpha + tot;
      pred[s] = (mm > 0.3);
      mem[s] = (mm < 0.3) ? mm : 0.0;
      if (!BUILD) {
        if (kp == s) outRow[h] = pred[s] ? 1.0f : 0.0f;  // slot s stored by kp==s
      }
    } else {
      pred[s] = false;
    }
  }
  const unsigned long long lt = (1ull << lane) - 1ull;
  if (BUILD) {
#pragma unroll
    for (int s = 0; s < NS; ++s) {
      const unsigned long long b = __ballot(pred[s]);
      if (kp == 0) {  // one writer group (wave-uniform)
        const int n = (int)__popcll(b);
        int base = 0;
        if (lane == 0 && n > 0) base = atomicAdd(cntOut, n);
        base = __shfl(base, 0);
        if (pred[s]) {
          const int rank = (int)__popcll(b & lt);
          listOut[base + rank] = (s * 256 + ht) * HNEXT;  // pre-multiplied
        }
      }
    }
  }
  if (XB) {  // build t+1 input list from prefetched xmask word (L5 only)
    if (doX && w < 11) {
      const int n = (int)__popcll(xw);
      int base = 0;
      if (lane == 0 && n > 0) base = atomicAdd(xCnt, n);
      base = __shfl(base, 0);
      if ((xw >> lane) & 1ull) {
        const int rank = (int)__popcll(xw & lt);
        xList[base + rank] = (w * 64 + lane) * 512;  // consumer L1: H=512
      }
    }
  }
  if (BUILD) __syncthreads();  // SYNC2: next layer's list + count ready
}

// 512 blocks x 1024 threads, one batch row per block. Steps 0..4 of the
// reference (zero-padded input) provably keep all state at 0, so only the
// 100 live steps run. List buffers: in[2] (per-step ping-pong), hL[2]
// (per-layer ping-pong: in->L1->h0->L2->h1->L3->h0->L4->h1->L5->h0->L6).
// Counter zeroing between lif calls is barrier-ordered: tid0 executes it
// after SYNC1/2 of the consumer; the producer's atomics run after its own
// SYNC1.
__global__ __launch_bounds__(1024, 8) void snn_main(
    const float* __restrict__ wsf, const unsigned long long* __restrict__ xmask,
    float* __restrict__ out) {
  const int tid = threadIdx.x;
  const int kp = tid >> 8;         // 0..3
  const int ht = tid & 255;
  const int lane = tid & 63;
  const int wv4 = (tid >> 6) & 3;
  const int w = tid >> 6;          // wave 0..15
  const int row = blockIdx.x;

  const float* WT1 = wsf + OFF1;
  const float* WT2 = wsf + OFF2;
  const float* WT3 = wsf + OFF3;
  const float* WT4 = wsf + OFF4;
  const float* WT5 = wsf + OFF5;
  const float* WT6 = wsf + OFF6;

  __shared__ double parts[2][4][3][256];  // 48 KB, ping-pong per layer
  __shared__ alignas(16) int hL[2][512];  // hidden packed lists
  __shared__ alignas(16) int inL[2][704]; // input packed lists (per-step)
  __shared__ int cH[2];
  __shared__ int inCnt[2];

  // Per-thread membrane state (f64); slot s covers neuron h = s*256 + ht.
  double m1[2] = {0.0, 0.0};
  double m2[1] = {0.0};
  double m3[1] = {0.0};
  double m4[1] = {0.0};
  double m5[2] = {0.0, 0.0};
  double m6[3] = {0.0, 0.0, 0.0};

  const double alpha = exp(-1.0 / 3.0);
  const unsigned long long lt = (1ull << lane) - 1ull;

  const unsigned long long* xmRow = xmask + (size_t)row * kWin * 12;
  float* outRowBase = out + (size_t)row * kWin * kNin;

  // Prologue: zero counters, build in[0] from xmask[t=0].
  unsigned long long b0 = 0;
  if (w < 11) b0 = xmRow[w];
  if (tid == 0) { cH[0] = 0; cH[1] = 0; inCnt[0] = 0; inCnt[1] = 0; }
  __syncthreads();
  if (w < 11) {
    const int n = (int)__popcll(b0);
    int base = 0;
    if (lane == 0 && n > 0) base = atomicAdd(&inCnt[0], n);
    base = __shfl(base, 0);
    if ((b0 >> lane) & 1ull) {
      const int rank = (int)__popcll(b0 & lt);
      inL[0][base + rank] = (w * 64 + lane) * 512;
    }
  }
  __syncthreads();

  for (int t = 0; t < kWin; ++t) {
    // Hoisted prefetch of next step's xmask word (consumed in L5 epilogue).
    const bool doX = (t + 1 < kWin);
    unsigned long long xw = 0;
    if (w < 11) xw = xmRow[(size_t)(doX ? (t + 1) : t) * 12 + w];

    lif<512, 256, true, false>(WT1, inL[t & 1], &inCnt[t & 1], hL[0], &cH[0],
                               parts[0], m1, alpha, nullptr, 0, false, nullptr,
                               nullptr, kp, ht, lane, wv4, w);
    lif<256, 128, true, false>(WT2, hL[0], &cH[0], hL[1], &cH[1],
                               parts[1], m2, alpha, nullptr, 0, false, nullptr,
                               nullptr, kp, ht, lane, wv4, w);
    if (tid == 0) cH[0] = 0;  // consumed by L2; L3 produces after its SYNC1
    lif<128, 256, true, false>(WT3, hL[1], &cH[1], hL[0], &cH[0],
                               parts[0], m3, alpha, nullptr, 0, false, nullptr,
                               nullptr, kp, ht, lane, wv4, w);
    if (tid == 0) cH[1] = 0;  // consumed by L3; L4 produces next
    lif<256, 512, true, false>(WT4, hL[0], &cH[0], hL[1], &cH[1],
                               parts[1], m4, alpha, nullptr, 0, false, nullptr,
                               nullptr, kp, ht, lane, wv4, w);
    if (tid == 0) { cH[0] = 0; inCnt[(t + 1) & 1] = 0; }  // L5 produces both
    lif<512, 700, true, true>(WT5, hL[1], &cH[1], hL[0], &cH[0],
                              parts[0], m5, alpha, nullptr, xw, doX,
                              inL[(t + 1) & 1], &inCnt[(t + 1) & 1],
                              kp, ht, lane, wv4, w);
    if (tid == 0) cH[1] = 0;  // consumed by L5; L2(t+1) produces next
    float* outRow = outRowBase + (size_t)t * kNin;
    lif<700, 1, false, false>(WT6, hL[0], &cH[0], nullptr, nullptr,
                              parts[1], m6, alpha, outRow, 0, false, nullptr,
                              nullptr, kp, ht, lane, wv4, w);
    if (tid == 0) cH[0] = 0;  // consumed by L6; L1(t+1) produces next
  }
}

}  // namespace

extern "C" void kernel_launch(void* const* d_in, const int* in_sizes, int n_in,
                              void* d_out, int out_size, void* d_ws, size_t ws_size,
                              hipStream_t stream) {
  const float* x = (const float*)d_in[0];
  float* ws = (float*)d_ws;
  unsigned long long* xm = (unsigned long long*)d_ws + XM_OFF_U64;
  float* out = (float*)d_out;

  // Transpose all weights into workspace (f32): dst[K][H] = W[H][K]^T.
  struct TK { int H, K; size_t off; int idx; };
  const TK tk[6] = {
      {512, 700, OFF1, 1},  // W_ih1
      {256, 512, OFF2, 2},  // W_h1h2
      {128, 256, OFF3, 3},  // W_h2h3
      {256, 128, OFF4, 4},  // W_h3h2
      {512, 256, OFF5, 5},  // W_h2h1
      {700, 512, OFF6, 6},  // W_h1o
  };
  for (int i = 0; i < 6; ++i) {
    const int n = tk[i].H * tk[i].K;
    transpose_k<<<(n + 255) / 256, 256, 0, stream>>>(
        (const float*)d_in[tk[i].idx], ws + tk[i].off, tk[i].H, tk[i].K);
  }

  // Precompute input spike bitmasks for all (row, t).
  xmask_k<<<512 * kWin, 256, 0, stream>>>(x, xm);

  snn_main<<<512, 1024, 0, stream>>>(ws, xm, out);
}